// Round 1
// baseline (197.739 us; speedup 1.0000x reference)
//
#include <hip/hip_runtime.h>

#define N_   8
#define C_   128
#define H_   96
#define W_   96
#define G_   8
#define GC_  16
#define HW_  (H_ * W_)       // 9216
#define CHW_ (C_ * HW_)      // 1179648
#define OM_  216
#define OMP_ 224             // padded: 8 groups x 28 rows (27 live + 1 pad)
#define OMROWS2_ 112         // packed dword rows per sample (224/2)
#define EPS_ 1e-5f
#define BLKS_PER_N_ 1152     // k_front blocks per sample (288*4)

typedef short bf16x8 __attribute__((ext_vector_type(8)));
typedef float f32x4 __attribute__((ext_vector_type(4)));

#if __has_builtin(__builtin_amdgcn_fdot2_f32_bf16)
#define HAVE_DOT2_ 1
typedef __bf16 bf16x2 __attribute__((ext_vector_type(2)));
static __device__ __forceinline__ bf16x2 u2bf2(unsigned int u) {
  union { unsigned int i; bf16x2 v; } c;
  c.i = u;
  return c.v;
}
#else
#define HAVE_DOT2_ 0
#endif

static __device__ __forceinline__ unsigned short f2bf(float f) {
  unsigned int u = __float_as_uint(f);
  unsigned int r = (u + 0x7fffu + ((u >> 16) & 1u)) >> 16;
  return (unsigned short)r;
}
static __device__ __forceinline__ float lo_bf(unsigned int u) {
  return __uint_as_float(u << 16);
}
static __device__ __forceinline__ float hi_bf(unsigned int u) {
  return __uint_as_float(u & 0xffff0000u);
}

// Branch-free exact-GELU via Abramowitz-Stegun 7.1.26 erf (|err| <= 1.5e-7,
// far below the bf16 quantization already applied to x1). ~14 inst,
// no divergent large-|x| path (libm erff has one).
static __device__ __forceinline__ float fast_gelu(float z) {
  float s = z * 0.70710678118654752f;
  float as = fabsf(s);
  float t = __builtin_amdgcn_rcpf(fmaf(0.3275911f, as, 1.0f));
  float e = __expf(-as * as);
  float inner = fmaf(fmaf(fmaf(fmaf(1.061405429f, t, -1.453152027f), t,
                               1.421413741f), t, -0.284496736f), t, 0.254829592f);
  float y = fmaf(-inner * t, e, 1.0f);          // erf(|s|)
  float erf_s = copysignf(y, s);
  float hz = 0.5f * z;
  return fmaf(hz, erf_s, hz);
}

// ---------------------------------------------------------------------------
// K1 (fused): single pass over x. Computes depthwise conv+bias (f32),
// emits: per-block sum/sumsq partials, conv output as bf16 NHWC (x1b,
// pre-norm), and group-planar raw x as bf16 (xgb) for the sampler.
// Grid (288, 4, 8), block (32,8): 32 px x 32 ch tile.
// ---------------------------------------------------------------------------
__global__ __launch_bounds__(256) void k_front(const float* __restrict__ x,
                                               const float* __restrict__ dw_w,
                                               const float* __restrict__ dw_b,
                                               unsigned short* __restrict__ xgb,
                                               unsigned short* __restrict__ x1b,
                                               float2* __restrict__ partials) {
  __shared__ float tile_c[32][33];   // raw center values (for xgb)
  __shared__ float tile_a[32][33];   // conv outputs (for x1b)
  __shared__ float ls[4], lq[4];
  int tx = threadIdx.x;
  int ty = threadIdx.y;
  int p0 = blockIdx.x * 32;
  int c0 = blockIdx.y * 32;
  int n = blockIdx.z;
  int p = p0 + tx;
  int h = p / W_;
  int w = p - h * W_;

  float s = 0.0f, q = 0.0f;
#pragma unroll
  for (int i = 0; i < 4; ++i) {
    int c = c0 + ty + i * 8;
    const float* wp = dw_w + c * 9;
    const float* xp = x + (n * C_ + c) * HW_;
    float acc = dw_b[c];
    float center = 0.0f;
#pragma unroll
    for (int dy = 0; dy < 3; ++dy) {
#pragma unroll
      for (int dx = 0; dx < 3; ++dx) {
        int yy = h + dy - 1;
        int xx = w + dx - 1;
        bool v = (yy >= 0) & (yy < H_) & (xx >= 0) & (xx < W_);
        float xin = v ? xp[yy * W_ + xx] : 0.0f;
        if (dy == 1 && dx == 1) center = xin;
        acc = fmaf(xin, wp[dy * 3 + dx], acc);
      }
    }
    tile_c[ty + i * 8][tx] = center;
    tile_a[ty + i * 8][tx] = acc;
    s += acc;
    q += acc * acc;
  }

  int tid = ty * 32 + tx;
#pragma unroll
  for (int o = 32; o > 0; o >>= 1) {
    s += __shfl_down(s, o);
    q += __shfl_down(q, o);
  }
  int lane = tid & 63;
  int wv = tid >> 6;
  if (lane == 0) { ls[wv] = s; lq[wv] = q; }
  __syncthreads();
  if (tid == 0) {
    int bid = blockIdx.x + 288 * blockIdx.y + BLKS_PER_N_ * n;
    partials[bid] = make_float2(ls[0] + ls[1] + ls[2] + ls[3],
                                lq[0] + lq[1] + lq[2] + lq[3]);
  }

  int c = c0 + tx;
  int g = c >> 4;
  int cc = c & 15;
#pragma unroll
  for (int i = 0; i < 4; ++i) {
    int pp = p0 + ty + i * 8;
    xgb[(((size_t)(n * G_ + g) * HW_) + pp) * GC_ + cc] = f2bf(tile_c[tx][ty + i * 8]);
    x1b[((size_t)(n * HW_) + pp) * C_ + c] = f2bf(tile_a[tx][ty + i * 8]);
  }
}

// ---------------------------------------------------------------------------
// K1b: reduce 1152 per-block partials per sample -> stats[n] = (sum, sumsq)
// ---------------------------------------------------------------------------
__global__ __launch_bounds__(256) void k_stats(const float2* __restrict__ partials,
                                               float* __restrict__ stats) {
  int n = blockIdx.x;
  int tid = threadIdx.x;
  const float2* p = partials + n * BLKS_PER_N_;
  float s = 0.0f, q = 0.0f;
  for (int i = tid; i < BLKS_PER_N_; i += 256) {
    float2 v = p[i];
    s += v.x;
    q += v.y;
  }
#pragma unroll
  for (int o = 32; o > 0; o >>= 1) {
    s += __shfl_down(s, o);
    q += __shfl_down(q, o);
  }
  __shared__ float ls[4], lq[4];
  int lane = tid & 63;
  int wv = tid >> 6;
  if (lane == 0) { ls[wv] = s; lq[wv] = q; }
  __syncthreads();
  if (tid == 0) {
    stats[n * 2 + 0] = ls[0] + ls[1] + ls[2] + ls[3];
    stats[n * 2 + 1] = lq[0] + lq[1] + lq[2] + lq[3];
  }
}

// ---------------------------------------------------------------------------
// K1c: permute+pad om_w -> A bf16 [224x128]: row o' = g*28+k holds om_w row
// g*27+k (k<27), zeros for k==27. Same permutation for bias (biasp).
// ---------------------------------------------------------------------------
__global__ __launch_bounds__(256) void k_prep(const float* __restrict__ om_w,
                                              const float* __restrict__ om_b,
                                              unsigned short* __restrict__ A,
                                              float* __restrict__ biasp) {
  int idx = blockIdx.x * 256 + threadIdx.x;   // 0 .. 224*128-1
  int o = idx >> 7;
  int cix = idx & 127;
  int g = o / 28;
  int k = o - g * 28;
  float v = (k < 27) ? om_w[(g * 27 + k) * C_ + cix] : 0.0f;
  A[idx] = f2bf(v);
  if (cix == 0) biasp[o] = (k < 27) ? om_b[g * 27 + k] : 0.0f;
}

// ---------------------------------------------------------------------------
// K4: MFMA GEMM with fused layernorm+GELU on the B operand.
// R9 restructure: 32-px tiles -> grid (288, 8) = 2304 blocks (was 576;
// occupancy was grid-limited at 23%). 4 waves/block split as 2 pixel-halves
// x 2 ot-halves (7 ot each). LDS 9.6 KB -> 8 blocks/CU resident; bfrag
// shrinks 32->16 VGPRs, staying in the 64-VGPR/8-wave tier. Fast branch-free
// erf replaces libm erff; biasp staged in LDS (was per-ot global loads).
// Output om2 bf16-packed (2 o-rows per dword).
// ---------------------------------------------------------------------------
__global__ __launch_bounds__(256) void k_gemm_mfma(const unsigned short* __restrict__ Bt,
                                                   const unsigned short* __restrict__ A,
                                                   const float* __restrict__ biasp,
                                                   const float* __restrict__ stats,
                                                   const float* __restrict__ gn_w,
                                                   const float* __restrict__ gn_b,
                                                   unsigned int* __restrict__ om2) {
  __shared__ unsigned short Bl[32 * 136];
  __shared__ alignas(16) float s_bias[OMP_];
  int tid = threadIdx.x;
  int pb = blockIdx.x;
  int n = blockIdx.y;
  int p0 = pb * 32;

  if (tid < OMP_ / 4) {
    ((float4*)s_bias)[tid] = ((const float4*)biasp)[tid];
  }

  float sum = stats[n * 2 + 0];
  float ssq = stats[n * 2 + 1];
  const float inv = 1.0f / (float)CHW_;
  float mean = sum * inv;
  float var = ssq * inv - mean * mean;
  float rstd = rsqrtf(var + EPS_);
  int cbase = (tid & 15) * 8;
  float a8[8], b8[8];
#pragma unroll
  for (int j = 0; j < 8; ++j) {
    float gw = gn_w[cbase + j];
    float gb = gn_b[cbase + j];
    a8[j] = rstd * gw;
    b8[j] = gb - mean * rstd * gw;
  }

  const unsigned short* src = Bt + ((size_t)n * HW_ + p0) * C_;
#pragma unroll
  for (int i = 0; i < 2; ++i) {
    int idx = i * 256 + tid;
    int row = idx >> 4;
    int col = idx & 15;                 // == tid & 15
    uint4 raw = *(const uint4*)(src + row * C_ + col * 8);
    unsigned int d[4] = {raw.x, raw.y, raw.z, raw.w};
    unsigned int od[4];
#pragma unroll
    for (int t = 0; t < 4; ++t) {
      float v0 = lo_bf(d[t]);
      float v1 = hi_bf(d[t]);
      float z0 = fmaf(v0, a8[2 * t], b8[2 * t]);
      float z1 = fmaf(v1, a8[2 * t + 1], b8[2 * t + 1]);
      float g0 = fast_gelu(z0);
      float g1 = fast_gelu(z1);
      od[t] = (unsigned int)f2bf(g0) | ((unsigned int)f2bf(g1) << 16);
    }
    uint4 packed = {od[0], od[1], od[2], od[3]};
    *(uint4*)(&Bl[row * 136 + col * 8]) = packed;
  }
  __syncthreads();

  int wave = tid >> 6;
  int lane = tid & 63;
  int quad = lane >> 4;
  int l16 = lane & 15;
  int pixhalf = wave & 1;               // which 16-px half of the tile
  int othalf = wave >> 1;               // which half of the 14 o-tiles
  int prow = pixhalf * 16 + l16;

  bf16x8 bfrag[4];
#pragma unroll
  for (int kk = 0; kk < 4; ++kk)
    bfrag[kk] = *(const bf16x8*)(&Bl[prow * 136 + kk * 32 + quad * 8]);

  int p = p0 + prow;
  for (int oi = 0; oi < 7; ++oi) {
    int ot = othalf * 7 + oi;
    const unsigned short* Ap = A + (ot * 16 + l16) * C_ + quad * 8;
    bf16x8 afrag[4];
#pragma unroll
    for (int kk = 0; kk < 4; ++kk)
      afrag[kk] = *(const bf16x8*)(Ap + kk * 32);

    f32x4 acc = {0.f, 0.f, 0.f, 0.f};
#pragma unroll
    for (int kk = 0; kk < 4; ++kk)
      acc = __builtin_amdgcn_mfma_f32_16x16x32_bf16(afrag[kk], bfrag[kk], acc, 0, 0, 0);

    int o0 = ot * 16 + quad * 4;               // even
    float4 bv = *(const float4*)(&s_bias[o0]);
    unsigned int pk0 = (unsigned int)f2bf(acc[0] + bv.x) |
                       ((unsigned int)f2bf(acc[1] + bv.y) << 16);
    unsigned int pk1 = (unsigned int)f2bf(acc[2] + bv.z) |
                       ((unsigned int)f2bf(acc[3] + bv.w) << 16);
    unsigned int* Cp = om2 + ((size_t)n * OMROWS2_ + (o0 >> 1)) * HW_ + p;
    Cp[0] = pk0;
    Cp[HW_] = pk1;
  }
}

// ---------------------------------------------------------------------------
// K5: deformable bilinear sampling from bf16 group-planar xgb.
// Phase 1 (576 jobs): redistribute 4 corner weights onto physical rows
// xs/xs+1, pack the two (y0,y1)-weights per x-row as a bf16 pair, and emit
// one int4 {pk_xrow0, pk_xrow1, off_y0, off_y1} per (pt,px).
// Phase 2: 4 lanes/px; per pt: 1 ds_read_b128 + 2 global dwordx4 +
// 8 v_perm + 8 v_dot2_f32_bf16 (pair = (v_y0, v_y1)). __shfl_xor(2) folds
// the two x-rows. Grid: 9216 blocks = 8n x 8g x 144 p-blocks.
// ---------------------------------------------------------------------------
__global__ __launch_bounds__(256) void k_sample(const unsigned short* __restrict__ xgb,
                                                const unsigned int* __restrict__ om2,
                                                float* __restrict__ out) {
  __shared__ int4 s_wa[9 * 64];   // {pk0, pk1, off_y0, off_y1}

  int tid = threadIdx.x;
  int ord = blockIdx.x;
  int n = ord & 7;
  int t2 = ord >> 3;
  int g = t2 & 7;
  int pb = t2 >> 3;
  int p0 = pb * 64;

  const unsigned int* omb = om2 + ((size_t)n * OMROWS2_ + g * 14) * HW_ + p0;
  for (int j = tid; j < 576; j += 256) {
    int pt = j >> 6;
    int px = j & 63;
    int p = p0 + px;
    int h = p / W_;
    int w = p - h * W_;
    unsigned int od = omb[pt * HW_ + px];
    float offx = lo_bf(od);
    float offy = hi_bf(od);
    unsigned int md = omb[(9 + (pt >> 1)) * HW_ + px];
    float m = (pt & 1) ? hi_bf(md) : lo_bf(md);
    float locy = (float)(h + pt / 3 - 1) + offy;
    float locx = (float)(w + pt % 3 - 1) + offx;
    float y0f = floorf(locy);
    float x0f = floorf(locx);
    float ly = locy - y0f;
    float lx = locx - x0f;
    int y0 = (int)y0f;
    int x0 = (int)x0f;
    int y1 = y0 + 1;
    int x1 = x0 + 1;
    bool vy0 = (y0 >= 0) & (y0 < H_);
    bool vy1 = (y1 >= 0) & (y1 < H_);
    bool vx0 = (x0 >= 0) & (x0 < W_);
    bool vx1 = (x1 >= 0) & (x1 < W_);
    float t0 = (1.0f - ly) * m;
    float t1 = ly * m;
    float u0 = 1.0f - lx;
    float w00 = (vy0 & vx0) ? t0 * u0 : 0.0f;
    float w01 = (vy0 & vx1) ? t0 * lx : 0.0f;
    float w10 = (vy1 & vx0) ? t1 * u0 : 0.0f;
    float w11 = (vy1 & vx1) ? t1 * lx : 0.0f;
    int yc0 = min(max(y0, 0), H_ - 1);
    int yc1 = min(max(y1, 0), H_ - 1);
    int xs  = min(max(x0, 0), W_ - 2);
    int idx0 = min(max(x0, 0), W_ - 1) - xs;       // 0 or 1
    int idx1 = min(max(x1, 0), W_ - 1) - xs;       // 0 or 1
    // row-weights: x-row0 = (y0: wr0y0, y1: wr0y1), x-row1 likewise
    float wr0y0 = (idx0 == 0 ? w00 : 0.0f) + (idx1 == 0 ? w01 : 0.0f);
    float wr1y0 = (idx0 == 1 ? w00 : 0.0f) + (idx1 == 1 ? w01 : 0.0f);
    float wr0y1 = (idx0 == 0 ? w10 : 0.0f) + (idx1 == 0 ? w11 : 0.0f);
    float wr1y1 = (idx0 == 1 ? w10 : 0.0f) + (idx1 == 1 ? w11 : 0.0f);
    int4 wa;
    wa.x = (int)((unsigned int)f2bf(wr0y0) | ((unsigned int)f2bf(wr0y1) << 16));
    wa.y = (int)((unsigned int)f2bf(wr1y0) | ((unsigned int)f2bf(wr1y1) << 16));
    wa.z = (yc0 * W_ + xs) * GC_;
    wa.w = (yc1 * W_ + xs) * GC_;
    s_wa[j] = wa;
  }
  __syncthreads();

  int px_l = tid >> 2;             // 0..63
  int sub = tid & 3;               // x-row = sub>>1, channel-chunk = sub&1
  int rowhalf = sub >> 1;
  int chunk = sub & 1;
  int p = p0 + px_l;
  const unsigned short* xbb = xgb + ((size_t)(n * G_ + g) * HW_) * GC_;

  float acc[8] = {0, 0, 0, 0, 0, 0, 0, 0};
#pragma unroll
  for (int pt = 0; pt < 9; ++pt) {
    int4 wa = s_wa[pt * 64 + px_l];
    unsigned int aw = (unsigned int)(rowhalf ? wa.y : wa.x);  // (w_y0, w_y1) bf16x2
    uint4 r0 = *(const uint4*)(xbb + wa.z + sub * 8);         // y0 row-pair
    uint4 r1 = *(const uint4*)(xbb + wa.w + sub * 8);         // y1 row-pair
    unsigned int d0[4] = {r0.x, r0.y, r0.z, r0.w};
    unsigned int d1[4] = {r1.x, r1.y, r1.z, r1.w};
#if HAVE_DOT2_
    bf16x2 a2 = u2bf2(aw);
#pragma unroll
    for (int t = 0; t < 4; ++t) {
      unsigned int blo = __builtin_amdgcn_perm(d1[t], d0[t], 0x05040100u); // (v0.lo, v1.lo)
      unsigned int bhi = __builtin_amdgcn_perm(d1[t], d0[t], 0x07060302u); // (v0.hi, v1.hi)
      acc[2 * t]     = __builtin_amdgcn_fdot2_f32_bf16(a2, u2bf2(blo), acc[2 * t], false);
      acc[2 * t + 1] = __builtin_amdgcn_fdot2_f32_bf16(a2, u2bf2(bhi), acc[2 * t + 1], false);
    }
#else
    float w0 = lo_bf(aw);
    float w1 = hi_bf(aw);
#pragma unroll
    for (int t = 0; t < 4; ++t) {
      acc[2 * t]     = fmaf(w0, lo_bf(d0[t]), acc[2 * t]);
      acc[2 * t + 1] = fmaf(w0, hi_bf(d0[t]), acc[2 * t + 1]);
      acc[2 * t]     = fmaf(w1, lo_bf(d1[t]), acc[2 * t]);
      acc[2 * t + 1] = fmaf(w1, hi_bf(d1[t]), acc[2 * t + 1]);
    }
#endif
  }

  // fold the two x-rows (lanes sub and sub^2 hold the same 8 channels)
#pragma unroll
  for (int i = 0; i < 8; ++i) acc[i] += __shfl_xor(acc[i], 2);

  int ch = chunk * 8 + rowhalf * 4;
  float* op = out + ((size_t)(n * C_ + g * GC_ + ch)) * HW_ + p;
#pragma unroll
  for (int r = 0; r < 4; ++r) op[r * HW_] = acc[rowhalf * 4 + r];
}

// ---------------------------------------------------------------------------
extern "C" void kernel_launch(void* const* d_in, const int* in_sizes, int n_in,
                              void* d_out, int out_size, void* d_ws, size_t ws_size,
                              hipStream_t stream) {
  const float* x    = (const float*)d_in[0];
  const float* dw_w = (const float*)d_in[1];
  const float* dw_b = (const float*)d_in[2];
  const float* gn_w = (const float*)d_in[3];
  const float* gn_b = (const float*)d_in[4];
  const float* om_w = (const float*)d_in[5];
  const float* om_b = (const float*)d_in[6];
  float* out = (float*)d_out;

  // workspace layout (~71 MB)
  unsigned short* xgb = (unsigned short*)d_ws;                       // 9437184 us
  unsigned short* x1b = xgb + (size_t)N_ * CHW_;                     // 9437184 us
  unsigned int* om2 = (unsigned int*)(x1b + (size_t)N_ * CHW_);      // 8*112*9216 u32
  float* stats = (float*)(om2 + (size_t)N_ * OMROWS2_ * HW_);        // 16 f
  float2* partials = (float2*)(stats + 16);                          // 9216 float2
  unsigned short* Abf = (unsigned short*)(partials + N_ * BLKS_PER_N_);
  float* biasp = (float*)(Abf + OMP_ * C_);                          // 224 f

  k_front<<<dim3(HW_ / 32, C_ / 32, N_), dim3(32, 8), 0, stream>>>(
      x, dw_w, dw_b, xgb, x1b, partials);
  k_stats<<<N_, 256, 0, stream>>>(partials, stats);
  k_prep<<<(OMP_ * C_) / 256, 256, 0, stream>>>(om_w, om_b, Abf, biasp);
  k_gemm_mfma<<<dim3(HW_ / 32, N_), 256, 0, stream>>>(
      x1b, Abf, biasp, stats, gn_w, gn_b, om2);
  k_sample<<<9216, 256, 0, stream>>>(xgb, om2, out);
}

// Round 2
// 189.690 us; speedup vs baseline: 1.0424x; 1.0424x over previous
//
#include <hip/hip_runtime.h>

#define N_   8
#define C_   128
#define H_   96
#define W_   96
#define G_   8
#define GC_  16
#define HW_  (H_ * W_)       // 9216
#define CHW_ (C_ * HW_)      // 1179648
#define OM_  216
#define OMP_ 224             // padded: 8 groups x 28 rows (27 live + 1 pad)
#define OMROWS2_ 112         // packed dword rows per sample (224/2)
#define EPS_ 1e-5f
#define BLKS_PER_N_ 96       // k_front blocks per sample (12 h-tiles * 8 groups)

typedef short bf16x8 __attribute__((ext_vector_type(8)));
typedef float f32x4 __attribute__((ext_vector_type(4)));

#if __has_builtin(__builtin_amdgcn_fdot2_f32_bf16)
#define HAVE_DOT2_ 1
typedef __bf16 bf16x2 __attribute__((ext_vector_type(2)));
static __device__ __forceinline__ bf16x2 u2bf2(unsigned int u) {
  union { unsigned int i; bf16x2 v; } c;
  c.i = u;
  return c.v;
}
#else
#define HAVE_DOT2_ 0
#endif

static __device__ __forceinline__ unsigned short f2bf(float f) {
  unsigned int u = __float_as_uint(f);
  unsigned int r = (u + 0x7fffu + ((u >> 16) & 1u)) >> 16;
  return (unsigned short)r;
}
static __device__ __forceinline__ float lo_bf(unsigned int u) {
  return __uint_as_float(u << 16);
}
static __device__ __forceinline__ float hi_bf(unsigned int u) {
  return __uint_as_float(u & 0xffff0000u);
}

// Branch-free exact-GELU via Abramowitz-Stegun 7.1.26 erf (|err| <= 1.5e-7,
// far below the bf16 quantization already applied to x1).
static __device__ __forceinline__ float fast_gelu(float z) {
  float s = z * 0.70710678118654752f;
  float as = fabsf(s);
  float t = __builtin_amdgcn_rcpf(fmaf(0.3275911f, as, 1.0f));
  float e = __expf(-as * as);
  float inner = fmaf(fmaf(fmaf(fmaf(1.061405429f, t, -1.453152027f), t,
                               1.421413741f), t, -0.284496736f), t, 0.254829592f);
  float y = fmaf(-inner * t, e, 1.0f);          // erf(|s|)
  float erf_s = copysignf(y, s);
  float hz = 0.5f * z;
  return fmaf(hz, erf_s, hz);
}

// Load one input row (5 cols: w0-1 .. w0+3) for a channel pair, zero-masked.
static __device__ __forceinline__ void loadrow5(float dst[2][5],
                                                const float* __restrict__ xp0,
                                                const float* __restrict__ xp1,
                                                int hh, int w0) {
  bool vy = (hh >= 0) & (hh < H_);
#pragma unroll
  for (int j = 0; j < 5; ++j) {
    int ww = w0 - 1 + j;
    bool v = vy & (ww >= 0) & (ww < W_);
    dst[0][j] = v ? xp0[hh * W_ + ww] : 0.0f;
    dst[1][j] = v ? xp1[hh * W_ + ww] : 0.0f;
  }
}

// ---------------------------------------------------------------------------
// K1 (fused, R10): 2-D tiles to kill the 3.3x vertical re-fetch (FETCH was
// 122 MB vs 37.7 MB ideal with 1-D 32-px strips). Block = 8 h-rows x 96 w x
// 16 ch (one group); grid (12, 8, 8). Thread = channel-pair x 3 px-cols,
// rolling 3-row x 5-col register window (3 loads/row/ch, not 9/output).
// Channel-pair ownership -> bf16x2 dwords packed in-register; pad-9 dword
// LDS tile (gcd(9,32)=1: conflict-free write AND read) transposes to
// px-major; two 4-row half-tiles keep LDS at 27.6 KB (~4 blocks/CU).
// Emits: per-block sum/sumsq partials, conv out bf16 NHWC (x1b), raw x
// bf16 group-planar (xgb). Over-fetch now (8+2)/8 = 1.25x.
// ---------------------------------------------------------------------------
__global__ __launch_bounds__(256) void k_front(const float* __restrict__ x,
                                               const float* __restrict__ dw_w,
                                               const float* __restrict__ dw_b,
                                               unsigned short* __restrict__ xgb,
                                               unsigned short* __restrict__ x1b,
                                               float2* __restrict__ partials) {
  __shared__ unsigned int lds_c[384 * 9];   // raw centers, packed bf16x2, pad 9
  __shared__ unsigned int lds_a[384 * 9];   // conv outputs, packed bf16x2
  __shared__ float ls[4], lq[4];

  int tx = threadIdx.x;          // 0..31 (px-column triple)
  int ty = threadIdx.y;          // 0..7  (channel pair)
  int tid = ty * 32 + tx;
  int hb = blockIdx.x;           // 0..11
  int g  = blockIdx.y;           // 0..7
  int n  = blockIdx.z;
  int h0 = hb * 8;
  int w0 = tx * 3;

  const int c0 = g * 16 + 2 * ty;
  float wk[2][9];
  const float* wp = dw_w + c0 * 9;
#pragma unroll
  for (int j = 0; j < 9; ++j) {
    wk[0][j] = wp[j];
    wk[1][j] = wp[9 + j];
  }
  float bias[2] = {dw_b[c0], dw_b[c0 + 1]};

  const float* xp0 = x + ((size_t)(n * C_ + c0)) * HW_;
  const float* xp1 = xp0 + HW_;

  float s = 0.0f, q = 0.0f;

#pragma unroll
  for (int half = 0; half < 2; ++half) {
    if (half) __syncthreads();             // LDS tile reuse across halves
    int hh0 = h0 + half * 4;

    float rr[3][2][5];
    loadrow5(rr[0], xp0, xp1, hh0 - 1, w0);
    loadrow5(rr[1], xp0, xp1, hh0,     w0);

#pragma unroll
    for (int r = 0; r < 4; ++r) {
      const int sA = r % 3;                // row hh0+r-1
      const int sB = (r + 1) % 3;          // row hh0+r
      const int sC = (r + 2) % 3;          // row hh0+r+1
      loadrow5(rr[sC], xp0, xp1, hh0 + r + 1, w0);

#pragma unroll
      for (int j = 0; j < 3; ++j) {
        float acc0 = bias[0], acc1 = bias[1];
#pragma unroll
        for (int dx = 0; dx < 3; ++dx) {
          acc0 = fmaf(rr[sA][0][j + dx], wk[0][0 + dx], acc0);
          acc1 = fmaf(rr[sA][1][j + dx], wk[1][0 + dx], acc1);
          acc0 = fmaf(rr[sB][0][j + dx], wk[0][3 + dx], acc0);
          acc1 = fmaf(rr[sB][1][j + dx], wk[1][3 + dx], acc1);
          acc0 = fmaf(rr[sC][0][j + dx], wk[0][6 + dx], acc0);
          acc1 = fmaf(rr[sC][1][j + dx], wk[1][6 + dx], acc1);
        }
        float cen0 = rr[sB][0][j + 1];
        float cen1 = rr[sB][1][j + 1];
        s += acc0 + acc1;
        q = fmaf(acc0, acc0, q);
        q = fmaf(acc1, acc1, q);
        int pxl = r * 96 + w0 + j;          // 0..383
        lds_a[pxl * 9 + ty] = (unsigned int)f2bf(acc0) |
                              ((unsigned int)f2bf(acc1) << 16);
        lds_c[pxl * 9 + ty] = (unsigned int)f2bf(cen0) |
                              ((unsigned int)f2bf(cen1) << 16);
      }
    }
    __syncthreads();

    // write-out: px-major, 32B per px per tile, fully coalesced
    for (int i = tid; i < 384; i += 256) {
      int p = h0 * W_ + half * 384 + i;     // rows are contiguous in p
      unsigned int wc[8], wa[8];
#pragma unroll
      for (int k = 0; k < 8; ++k) {
        wc[k] = lds_c[i * 9 + k];
        wa[k] = lds_a[i * 9 + k];
      }
      unsigned int* xg = (unsigned int*)xgb + ((size_t)(n * G_ + g) * HW_ + p) * 8;
      uint4 c01 = {wc[0], wc[1], wc[2], wc[3]};
      uint4 c23 = {wc[4], wc[5], wc[6], wc[7]};
      *(uint4*)xg = c01;
      *(uint4*)(xg + 4) = c23;
      unsigned int* xb = (unsigned int*)x1b + ((size_t)n * HW_ + p) * 64 + g * 8;
      uint4 a01 = {wa[0], wa[1], wa[2], wa[3]};
      uint4 a23 = {wa[4], wa[5], wa[6], wa[7]};
      *(uint4*)xb = a01;
      *(uint4*)(xb + 4) = a23;
    }
  }

  // block reduction of sum/sumsq
#pragma unroll
  for (int o = 32; o > 0; o >>= 1) {
    s += __shfl_down(s, o);
    q += __shfl_down(q, o);
  }
  int lane = tid & 63;
  int wv = tid >> 6;
  if (lane == 0) { ls[wv] = s; lq[wv] = q; }
  __syncthreads();
  if (tid == 0) {
    int bid = hb + 12 * g + BLKS_PER_N_ * n;
    partials[bid] = make_float2(ls[0] + ls[1] + ls[2] + ls[3],
                                lq[0] + lq[1] + lq[2] + lq[3]);
  }
}

// ---------------------------------------------------------------------------
// K1b+K1c merged (one launch): blocks 0..7 reduce partials -> stats[n];
// blocks 8..119 permute+pad om_w -> A bf16 [224x128] and biasp.
// ---------------------------------------------------------------------------
__global__ __launch_bounds__(256) void k_stats_prep(const float2* __restrict__ partials,
                                                    float* __restrict__ stats,
                                                    const float* __restrict__ om_w,
                                                    const float* __restrict__ om_b,
                                                    unsigned short* __restrict__ A,
                                                    float* __restrict__ biasp) {
  __shared__ float ls[4], lq[4];
  int b = blockIdx.x;
  int tid = threadIdx.x;
  if (b < N_) {
    int n = b;
    const float2* p = partials + n * BLKS_PER_N_;
    float s = 0.0f, q = 0.0f;
    if (tid < BLKS_PER_N_) {
      float2 v = p[tid];
      s = v.x;
      q = v.y;
    }
#pragma unroll
    for (int o = 32; o > 0; o >>= 1) {
      s += __shfl_down(s, o);
      q += __shfl_down(q, o);
    }
    int lane = tid & 63;
    int wv = tid >> 6;
    if (lane == 0) { ls[wv] = s; lq[wv] = q; }
    __syncthreads();
    if (tid == 0) {
      stats[n * 2 + 0] = ls[0] + ls[1] + ls[2] + ls[3];
      stats[n * 2 + 1] = lq[0] + lq[1] + lq[2] + lq[3];
    }
  } else {
    int idx = (b - N_) * 256 + tid;       // 0 .. 224*128-1
    int o = idx >> 7;
    int cix = idx & 127;
    int gg = o / 28;
    int k = o - gg * 28;
    float v = (k < 27) ? om_w[(gg * 27 + k) * C_ + cix] : 0.0f;
    A[idx] = f2bf(v);
    if (cix == 0) biasp[o] = (k < 27) ? om_b[gg * 27 + k] : 0.0f;
  }
}

// ---------------------------------------------------------------------------
// K4: MFMA GEMM with fused layernorm+GELU on the B operand.
// 32-px tiles -> grid (288, 8) = 2304 blocks; 4 waves/block split as
// 2 pixel-halves x 2 ot-halves (7 ot each). Output om2 bf16-packed.
// ---------------------------------------------------------------------------
__global__ __launch_bounds__(256) void k_gemm_mfma(const unsigned short* __restrict__ Bt,
                                                   const unsigned short* __restrict__ A,
                                                   const float* __restrict__ biasp,
                                                   const float* __restrict__ stats,
                                                   const float* __restrict__ gn_w,
                                                   const float* __restrict__ gn_b,
                                                   unsigned int* __restrict__ om2) {
  __shared__ unsigned short Bl[32 * 136];
  __shared__ alignas(16) float s_bias[OMP_];
  int tid = threadIdx.x;
  int pb = blockIdx.x;
  int n = blockIdx.y;
  int p0 = pb * 32;

  if (tid < OMP_ / 4) {
    ((float4*)s_bias)[tid] = ((const float4*)biasp)[tid];
  }

  float sum = stats[n * 2 + 0];
  float ssq = stats[n * 2 + 1];
  const float inv = 1.0f / (float)CHW_;
  float mean = sum * inv;
  float var = ssq * inv - mean * mean;
  float rstd = rsqrtf(var + EPS_);
  int cbase = (tid & 15) * 8;
  float a8[8], b8[8];
#pragma unroll
  for (int j = 0; j < 8; ++j) {
    float gw = gn_w[cbase + j];
    float gb = gn_b[cbase + j];
    a8[j] = rstd * gw;
    b8[j] = gb - mean * rstd * gw;
  }

  const unsigned short* src = Bt + ((size_t)n * HW_ + p0) * C_;
#pragma unroll
  for (int i = 0; i < 2; ++i) {
    int idx = i * 256 + tid;
    int row = idx >> 4;
    int col = idx & 15;                 // == tid & 15
    uint4 raw = *(const uint4*)(src + row * C_ + col * 8);
    unsigned int d[4] = {raw.x, raw.y, raw.z, raw.w};
    unsigned int od[4];
#pragma unroll
    for (int t = 0; t < 4; ++t) {
      float v0 = lo_bf(d[t]);
      float v1 = hi_bf(d[t]);
      float z0 = fmaf(v0, a8[2 * t], b8[2 * t]);
      float z1 = fmaf(v1, a8[2 * t + 1], b8[2 * t + 1]);
      float g0 = fast_gelu(z0);
      float g1 = fast_gelu(z1);
      od[t] = (unsigned int)f2bf(g0) | ((unsigned int)f2bf(g1) << 16);
    }
    uint4 packed = {od[0], od[1], od[2], od[3]};
    *(uint4*)(&Bl[row * 136 + col * 8]) = packed;
  }
  __syncthreads();

  int wave = tid >> 6;
  int lane = tid & 63;
  int quad = lane >> 4;
  int l16 = lane & 15;
  int pixhalf = wave & 1;               // which 16-px half of the tile
  int othalf = wave >> 1;               // which half of the 14 o-tiles
  int prow = pixhalf * 16 + l16;

  bf16x8 bfrag[4];
#pragma unroll
  for (int kk = 0; kk < 4; ++kk)
    bfrag[kk] = *(const bf16x8*)(&Bl[prow * 136 + kk * 32 + quad * 8]);

  int p = p0 + prow;
  for (int oi = 0; oi < 7; ++oi) {
    int ot = othalf * 7 + oi;
    const unsigned short* Ap = A + (ot * 16 + l16) * C_ + quad * 8;
    bf16x8 afrag[4];
#pragma unroll
    for (int kk = 0; kk < 4; ++kk)
      afrag[kk] = *(const bf16x8*)(Ap + kk * 32);

    f32x4 acc = {0.f, 0.f, 0.f, 0.f};
#pragma unroll
    for (int kk = 0; kk < 4; ++kk)
      acc = __builtin_amdgcn_mfma_f32_16x16x32_bf16(afrag[kk], bfrag[kk], acc, 0, 0, 0);

    int o0 = ot * 16 + quad * 4;               // even
    float4 bv = *(const float4*)(&s_bias[o0]);
    unsigned int pk0 = (unsigned int)f2bf(acc[0] + bv.x) |
                       ((unsigned int)f2bf(acc[1] + bv.y) << 16);
    unsigned int pk1 = (unsigned int)f2bf(acc[2] + bv.z) |
                       ((unsigned int)f2bf(acc[3] + bv.w) << 16);
    unsigned int* Cp = om2 + ((size_t)n * OMROWS2_ + (o0 >> 1)) * HW_ + p;
    Cp[0] = pk0;
    Cp[HW_] = pk1;
  }
}

// ---------------------------------------------------------------------------
// K5: deformable bilinear sampling from bf16 group-planar xgb.
// ---------------------------------------------------------------------------
__global__ __launch_bounds__(256) void k_sample(const unsigned short* __restrict__ xgb,
                                                const unsigned int* __restrict__ om2,
                                                float* __restrict__ out) {
  __shared__ int4 s_wa[9 * 64];   // {pk0, pk1, off_y0, off_y1}

  int tid = threadIdx.x;
  int ord = blockIdx.x;
  int n = ord & 7;
  int t2 = ord >> 3;
  int g = t2 & 7;
  int pb = t2 >> 3;
  int p0 = pb * 64;

  const unsigned int* omb = om2 + ((size_t)n * OMROWS2_ + g * 14) * HW_ + p0;
  for (int j = tid; j < 576; j += 256) {
    int pt = j >> 6;
    int px = j & 63;
    int p = p0 + px;
    int h = p / W_;
    int w = p - h * W_;
    unsigned int od = omb[pt * HW_ + px];
    float offx = lo_bf(od);
    float offy = hi_bf(od);
    unsigned int md = omb[(9 + (pt >> 1)) * HW_ + px];
    float m = (pt & 1) ? hi_bf(md) : lo_bf(md);
    float locy = (float)(h + pt / 3 - 1) + offy;
    float locx = (float)(w + pt % 3 - 1) + offx;
    float y0f = floorf(locy);
    float x0f = floorf(locx);
    float ly = locy - y0f;
    float lx = locx - x0f;
    int y0 = (int)y0f;
    int x0 = (int)x0f;
    int y1 = y0 + 1;
    int x1 = x0 + 1;
    bool vy0 = (y0 >= 0) & (y0 < H_);
    bool vy1 = (y1 >= 0) & (y1 < H_);
    bool vx0 = (x0 >= 0) & (x0 < W_);
    bool vx1 = (x1 >= 0) & (x1 < W_);
    float t0 = (1.0f - ly) * m;
    float t1 = ly * m;
    float u0 = 1.0f - lx;
    float w00 = (vy0 & vx0) ? t0 * u0 : 0.0f;
    float w01 = (vy0 & vx1) ? t0 * lx : 0.0f;
    float w10 = (vy1 & vx0) ? t1 * u0 : 0.0f;
    float w11 = (vy1 & vx1) ? t1 * lx : 0.0f;
    int yc0 = min(max(y0, 0), H_ - 1);
    int yc1 = min(max(y1, 0), H_ - 1);
    int xs  = min(max(x0, 0), W_ - 2);
    int idx0 = min(max(x0, 0), W_ - 1) - xs;       // 0 or 1
    int idx1 = min(max(x1, 0), W_ - 1) - xs;       // 0 or 1
    float wr0y0 = (idx0 == 0 ? w00 : 0.0f) + (idx1 == 0 ? w01 : 0.0f);
    float wr1y0 = (idx0 == 1 ? w00 : 0.0f) + (idx1 == 1 ? w01 : 0.0f);
    float wr0y1 = (idx0 == 0 ? w10 : 0.0f) + (idx1 == 0 ? w11 : 0.0f);
    float wr1y1 = (idx0 == 1 ? w10 : 0.0f) + (idx1 == 1 ? w11 : 0.0f);
    int4 wa;
    wa.x = (int)((unsigned int)f2bf(wr0y0) | ((unsigned int)f2bf(wr0y1) << 16));
    wa.y = (int)((unsigned int)f2bf(wr1y0) | ((unsigned int)f2bf(wr1y1) << 16));
    wa.z = (yc0 * W_ + xs) * GC_;
    wa.w = (yc1 * W_ + xs) * GC_;
    s_wa[j] = wa;
  }
  __syncthreads();

  int px_l = tid >> 2;             // 0..63
  int sub = tid & 3;               // x-row = sub>>1, channel-chunk = sub&1
  int rowhalf = sub >> 1;
  int chunk = sub & 1;
  int p = p0 + px_l;
  const unsigned short* xbb = xgb + ((size_t)(n * G_ + g) * HW_) * GC_;

  float acc[8] = {0, 0, 0, 0, 0, 0, 0, 0};
#pragma unroll
  for (int pt = 0; pt < 9; ++pt) {
    int4 wa = s_wa[pt * 64 + px_l];
    unsigned int aw = (unsigned int)(rowhalf ? wa.y : wa.x);  // (w_y0, w_y1) bf16x2
    uint4 r0 = *(const uint4*)(xbb + wa.z + sub * 8);         // y0 row-pair
    uint4 r1 = *(const uint4*)(xbb + wa.w + sub * 8);         // y1 row-pair
    unsigned int d0[4] = {r0.x, r0.y, r0.z, r0.w};
    unsigned int d1[4] = {r1.x, r1.y, r1.z, r1.w};
#if HAVE_DOT2_
    bf16x2 a2 = u2bf2(aw);
#pragma unroll
    for (int t = 0; t < 4; ++t) {
      unsigned int blo = __builtin_amdgcn_perm(d1[t], d0[t], 0x05040100u); // (v0.lo, v1.lo)
      unsigned int bhi = __builtin_amdgcn_perm(d1[t], d0[t], 0x07060302u); // (v0.hi, v1.hi)
      acc[2 * t]     = __builtin_amdgcn_fdot2_f32_bf16(a2, u2bf2(blo), acc[2 * t], false);
      acc[2 * t + 1] = __builtin_amdgcn_fdot2_f32_bf16(a2, u2bf2(bhi), acc[2 * t + 1], false);
    }
#else
    float w0 = lo_bf(aw);
    float w1 = hi_bf(aw);
#pragma unroll
    for (int t = 0; t < 4; ++t) {
      acc[2 * t]     = fmaf(w0, lo_bf(d0[t]), acc[2 * t]);
      acc[2 * t + 1] = fmaf(w0, hi_bf(d0[t]), acc[2 * t + 1]);
      acc[2 * t]     = fmaf(w1, lo_bf(d1[t]), acc[2 * t]);
      acc[2 * t + 1] = fmaf(w1, hi_bf(d1[t]), acc[2 * t + 1]);
    }
#endif
  }

  // fold the two x-rows (lanes sub and sub^2 hold the same 8 channels)
#pragma unroll
  for (int i = 0; i < 8; ++i) acc[i] += __shfl_xor(acc[i], 2);

  int ch = chunk * 8 + rowhalf * 4;
  float* op = out + ((size_t)(n * C_ + g * GC_ + ch)) * HW_ + p;
#pragma unroll
  for (int r = 0; r < 4; ++r) op[r * HW_] = acc[rowhalf * 4 + r];
}

// ---------------------------------------------------------------------------
extern "C" void kernel_launch(void* const* d_in, const int* in_sizes, int n_in,
                              void* d_out, int out_size, void* d_ws, size_t ws_size,
                              hipStream_t stream) {
  const float* x    = (const float*)d_in[0];
  const float* dw_w = (const float*)d_in[1];
  const float* dw_b = (const float*)d_in[2];
  const float* gn_w = (const float*)d_in[3];
  const float* gn_b = (const float*)d_in[4];
  const float* om_w = (const float*)d_in[5];
  const float* om_b = (const float*)d_in[6];
  float* out = (float*)d_out;

  // workspace layout (~71 MB)
  unsigned short* xgb = (unsigned short*)d_ws;                       // 9437184 us
  unsigned short* x1b = xgb + (size_t)N_ * CHW_;                     // 9437184 us
  unsigned int* om2 = (unsigned int*)(x1b + (size_t)N_ * CHW_);      // 8*112*9216 u32
  float* stats = (float*)(om2 + (size_t)N_ * OMROWS2_ * HW_);        // 16 f
  float2* partials = (float2*)(stats + 16);                          // 768 float2
  unsigned short* Abf = (unsigned short*)(partials + N_ * BLKS_PER_N_);
  float* biasp = (float*)(Abf + OMP_ * C_);                          // 224 f

  k_front<<<dim3(12, G_, N_), dim3(32, 8), 0, stream>>>(
      x, dw_w, dw_b, xgb, x1b, partials);
  k_stats_prep<<<N_ + 112, 256, 0, stream>>>(partials, stats, om_w, om_b, Abf, biasp);
  k_gemm_mfma<<<dim3(HW_ / 32, N_), 256, 0, stream>>>(
      x1b, Abf, biasp, stats, gn_w, gn_b, om2);
  k_sample<<<9216, 256, 0, stream>>>(xgb, om2, out);
}

// Round 3
// 181.797 us; speedup vs baseline: 1.0877x; 1.0434x over previous
//
#include <hip/hip_runtime.h>

#define N_   8
#define C_   128
#define H_   96
#define W_   96
#define G_   8
#define GC_  16
#define HW_  (H_ * W_)       // 9216
#define CHW_ (C_ * HW_)      // 1179648
#define OM_  216
#define OMP_ 224             // padded: 8 groups x 28 rows (27 live + 1 pad)
#define OMROWS2_ 112         // packed dword rows per sample (224/2)
#define EPS_ 1e-5f
#define BLKS_PER_N_ 192      // k_front blocks per sample (24 h-tiles * 8 groups)

typedef short bf16x8 __attribute__((ext_vector_type(8)));
typedef float f32x4 __attribute__((ext_vector_type(4)));

#if __has_builtin(__builtin_amdgcn_fdot2_f32_bf16)
#define HAVE_DOT2_ 1
typedef __bf16 bf16x2 __attribute__((ext_vector_type(2)));
static __device__ __forceinline__ bf16x2 u2bf2(unsigned int u) {
  union { unsigned int i; bf16x2 v; } c;
  c.i = u;
  return c.v;
}
#else
#define HAVE_DOT2_ 0
#endif

static __device__ __forceinline__ unsigned short f2bf(float f) {
  unsigned int u = __float_as_uint(f);
  unsigned int r = (u + 0x7fffu + ((u >> 16) & 1u)) >> 16;
  return (unsigned short)r;
}
static __device__ __forceinline__ float lo_bf(unsigned int u) {
  return __uint_as_float(u << 16);
}
static __device__ __forceinline__ float hi_bf(unsigned int u) {
  return __uint_as_float(u & 0xffff0000u);
}

// Branch-free exact-GELU via Abramowitz-Stegun 7.1.26 erf (|err| <= 1.5e-7,
// far below the bf16 quantization already applied to x1).
static __device__ __forceinline__ float fast_gelu(float z) {
  float s = z * 0.70710678118654752f;
  float as = fabsf(s);
  float t = __builtin_amdgcn_rcpf(fmaf(0.3275911f, as, 1.0f));
  float e = __expf(-as * as);
  float inner = fmaf(fmaf(fmaf(fmaf(1.061405429f, t, -1.453152027f), t,
                               1.421413741f), t, -0.284496736f), t, 0.254829592f);
  float y = fmaf(-inner * t, e, 1.0f);          // erf(|s|)
  float erf_s = copysignf(y, s);
  float hz = 0.5f * z;
  return fmaf(hz, erf_s, hz);
}

// Load one input row (5 cols: w0-1 .. w0+3) for a channel pair, zero-masked.
static __device__ __forceinline__ void loadrow5(float dst[2][5],
                                                const float* __restrict__ xp0,
                                                const float* __restrict__ xp1,
                                                int hh, int w0) {
  bool vy = (hh >= 0) & (hh < H_);
#pragma unroll
  for (int j = 0; j < 5; ++j) {
    int ww = w0 - 1 + j;
    bool v = vy & (ww >= 0) & (ww < W_);
    dst[0][j] = v ? xp0[hh * W_ + ww] : 0.0f;
    dst[1][j] = v ? xp1[hh * W_ + ww] : 0.0f;
  }
}

// ---------------------------------------------------------------------------
// K1 (fused, R11): R10's 2-D tile killed the over-fetch (122->24 MB) but was
// grid-limited: 768 blocks = 3/CU, Occupancy 17%, hbm 1.5 TB/s ->
// latency-bound. R11 splits each block's two 4-row halves into separate
// blocks: tile = 4 h x 96 w x 16 ch, grid (24, 8, 8) = 1536 blocks; LDS
// 27.6 KB -> 5 blocks/CU = 20 waves/CU (62%). Halo over-fetch 1.25->1.5x
// (~+6 MB) -- cheap against 3.6x more latency hiding. Thread = channel-pair
// x 3 px-cols, rolling 3x5 register window; pad-9 dword LDS transpose to
// px-major; packed bf16x2 stores.
// ---------------------------------------------------------------------------
__global__ __launch_bounds__(256) void k_front(const float* __restrict__ x,
                                               const float* __restrict__ dw_w,
                                               const float* __restrict__ dw_b,
                                               unsigned short* __restrict__ xgb,
                                               unsigned short* __restrict__ x1b,
                                               float2* __restrict__ partials) {
  __shared__ unsigned int lds_c[384 * 9];   // raw centers, packed bf16x2, pad 9
  __shared__ unsigned int lds_a[384 * 9];   // conv outputs, packed bf16x2
  __shared__ float ls[4], lq[4];

  int tx = threadIdx.x;          // 0..31 (px-column triple)
  int ty = threadIdx.y;          // 0..7  (channel pair)
  int tid = ty * 32 + tx;
  int hb = blockIdx.x;           // 0..23
  int g  = blockIdx.y;           // 0..7
  int n  = blockIdx.z;
  int h0 = hb * 4;
  int w0 = tx * 3;

  const int c0 = g * 16 + 2 * ty;
  float wk[2][9];
  const float* wp = dw_w + c0 * 9;
#pragma unroll
  for (int j = 0; j < 9; ++j) {
    wk[0][j] = wp[j];
    wk[1][j] = wp[9 + j];
  }
  float bias[2] = {dw_b[c0], dw_b[c0 + 1]};

  const float* xp0 = x + ((size_t)(n * C_ + c0)) * HW_;
  const float* xp1 = xp0 + HW_;

  float s = 0.0f, q = 0.0f;

  float rr[3][2][5];
  loadrow5(rr[0], xp0, xp1, h0 - 1, w0);
  loadrow5(rr[1], xp0, xp1, h0,     w0);

#pragma unroll
  for (int r = 0; r < 4; ++r) {
    const int sA = r % 3;                // row h0+r-1
    const int sB = (r + 1) % 3;          // row h0+r
    const int sC = (r + 2) % 3;          // row h0+r+1
    loadrow5(rr[sC], xp0, xp1, h0 + r + 1, w0);

#pragma unroll
    for (int j = 0; j < 3; ++j) {
      float acc0 = bias[0], acc1 = bias[1];
#pragma unroll
      for (int dx = 0; dx < 3; ++dx) {
        acc0 = fmaf(rr[sA][0][j + dx], wk[0][0 + dx], acc0);
        acc1 = fmaf(rr[sA][1][j + dx], wk[1][0 + dx], acc1);
        acc0 = fmaf(rr[sB][0][j + dx], wk[0][3 + dx], acc0);
        acc1 = fmaf(rr[sB][1][j + dx], wk[1][3 + dx], acc1);
        acc0 = fmaf(rr[sC][0][j + dx], wk[0][6 + dx], acc0);
        acc1 = fmaf(rr[sC][1][j + dx], wk[1][6 + dx], acc1);
      }
      float cen0 = rr[sB][0][j + 1];
      float cen1 = rr[sB][1][j + 1];
      s += acc0 + acc1;
      q = fmaf(acc0, acc0, q);
      q = fmaf(acc1, acc1, q);
      int pxl = r * 96 + w0 + j;          // 0..383
      lds_a[pxl * 9 + ty] = (unsigned int)f2bf(acc0) |
                            ((unsigned int)f2bf(acc1) << 16);
      lds_c[pxl * 9 + ty] = (unsigned int)f2bf(cen0) |
                            ((unsigned int)f2bf(cen1) << 16);
    }
  }
  __syncthreads();

  // write-out: px-major, 32B per px per tile, fully coalesced
  for (int i = tid; i < 384; i += 256) {
    int p = h0 * W_ + i;                  // rows are contiguous in p
    unsigned int wc[8], wa[8];
#pragma unroll
    for (int k = 0; k < 8; ++k) {
      wc[k] = lds_c[i * 9 + k];
      wa[k] = lds_a[i * 9 + k];
    }
    unsigned int* xg = (unsigned int*)xgb + ((size_t)(n * G_ + g) * HW_ + p) * 8;
    uint4 c01 = {wc[0], wc[1], wc[2], wc[3]};
    uint4 c23 = {wc[4], wc[5], wc[6], wc[7]};
    *(uint4*)xg = c01;
    *(uint4*)(xg + 4) = c23;
    unsigned int* xb = (unsigned int*)x1b + ((size_t)n * HW_ + p) * 64 + g * 8;
    uint4 a01 = {wa[0], wa[1], wa[2], wa[3]};
    uint4 a23 = {wa[4], wa[5], wa[6], wa[7]};
    *(uint4*)xb = a01;
    *(uint4*)(xb + 4) = a23;
  }

  // block reduction of sum/sumsq
#pragma unroll
  for (int o = 32; o > 0; o >>= 1) {
    s += __shfl_down(s, o);
    q += __shfl_down(q, o);
  }
  int lane = tid & 63;
  int wv = tid >> 6;
  if (lane == 0) { ls[wv] = s; lq[wv] = q; }
  __syncthreads();
  if (tid == 0) {
    int bid = hb + 24 * g + BLKS_PER_N_ * n;
    partials[bid] = make_float2(ls[0] + ls[1] + ls[2] + ls[3],
                                lq[0] + lq[1] + lq[2] + lq[3]);
  }
}

// ---------------------------------------------------------------------------
// K1b+K1c merged (one launch): blocks 0..7 reduce partials -> stats[n];
// blocks 8..119 permute+pad om_w -> A bf16 [224x128] and biasp.
// ---------------------------------------------------------------------------
__global__ __launch_bounds__(256) void k_stats_prep(const float2* __restrict__ partials,
                                                    float* __restrict__ stats,
                                                    const float* __restrict__ om_w,
                                                    const float* __restrict__ om_b,
                                                    unsigned short* __restrict__ A,
                                                    float* __restrict__ biasp) {
  __shared__ float ls[4], lq[4];
  int b = blockIdx.x;
  int tid = threadIdx.x;
  if (b < N_) {
    int n = b;
    const float2* p = partials + n * BLKS_PER_N_;
    float s = 0.0f, q = 0.0f;
    if (tid < BLKS_PER_N_) {
      float2 v = p[tid];
      s = v.x;
      q = v.y;
    }
#pragma unroll
    for (int o = 32; o > 0; o >>= 1) {
      s += __shfl_down(s, o);
      q += __shfl_down(q, o);
    }
    int lane = tid & 63;
    int wv = tid >> 6;
    if (lane == 0) { ls[wv] = s; lq[wv] = q; }
    __syncthreads();
    if (tid == 0) {
      stats[n * 2 + 0] = ls[0] + ls[1] + ls[2] + ls[3];
      stats[n * 2 + 1] = lq[0] + lq[1] + lq[2] + lq[3];
    }
  } else {
    int idx = (b - N_) * 256 + tid;       // 0 .. 224*128-1
    int o = idx >> 7;
    int cix = idx & 127;
    int gg = o / 28;
    int k = o - gg * 28;
    float v = (k < 27) ? om_w[(gg * 27 + k) * C_ + cix] : 0.0f;
    A[idx] = f2bf(v);
    if (cix == 0) biasp[o] = (k < 27) ? om_b[gg * 27 + k] : 0.0f;
  }
}

// ---------------------------------------------------------------------------
// K4: MFMA GEMM with fused layernorm+GELU on the B operand.
// 32-px tiles -> grid (288, 8) = 2304 blocks; 4 waves/block split as
// 2 pixel-halves x 2 ot-halves (7 ot each). Output om2 bf16-packed.
// ---------------------------------------------------------------------------
__global__ __launch_bounds__(256) void k_gemm_mfma(const unsigned short* __restrict__ Bt,
                                                   const unsigned short* __restrict__ A,
                                                   const float* __restrict__ biasp,
                                                   const float* __restrict__ stats,
                                                   const float* __restrict__ gn_w,
                                                   const float* __restrict__ gn_b,
                                                   unsigned int* __restrict__ om2) {
  __shared__ unsigned short Bl[32 * 136];
  __shared__ alignas(16) float s_bias[OMP_];
  int tid = threadIdx.x;
  int pb = blockIdx.x;
  int n = blockIdx.y;
  int p0 = pb * 32;

  if (tid < OMP_ / 4) {
    ((float4*)s_bias)[tid] = ((const float4*)biasp)[tid];
  }

  float sum = stats[n * 2 + 0];
  float ssq = stats[n * 2 + 1];
  const float inv = 1.0f / (float)CHW_;
  float mean = sum * inv;
  float var = ssq * inv - mean * mean;
  float rstd = rsqrtf(var + EPS_);
  int cbase = (tid & 15) * 8;
  float a8[8], b8[8];
#pragma unroll
  for (int j = 0; j < 8; ++j) {
    float gw = gn_w[cbase + j];
    float gb = gn_b[cbase + j];
    a8[j] = rstd * gw;
    b8[j] = gb - mean * rstd * gw;
  }

  const unsigned short* src = Bt + ((size_t)n * HW_ + p0) * C_;
#pragma unroll
  for (int i = 0; i < 2; ++i) {
    int idx = i * 256 + tid;
    int row = idx >> 4;
    int col = idx & 15;                 // == tid & 15
    uint4 raw = *(const uint4*)(src + row * C_ + col * 8);
    unsigned int d[4] = {raw.x, raw.y, raw.z, raw.w};
    unsigned int od[4];
#pragma unroll
    for (int t = 0; t < 4; ++t) {
      float v0 = lo_bf(d[t]);
      float v1 = hi_bf(d[t]);
      float z0 = fmaf(v0, a8[2 * t], b8[2 * t]);
      float z1 = fmaf(v1, a8[2 * t + 1], b8[2 * t + 1]);
      float g0 = fast_gelu(z0);
      float g1 = fast_gelu(z1);
      od[t] = (unsigned int)f2bf(g0) | ((unsigned int)f2bf(g1) << 16);
    }
    uint4 packed = {od[0], od[1], od[2], od[3]};
    *(uint4*)(&Bl[row * 136 + col * 8]) = packed;
  }
  __syncthreads();

  int wave = tid >> 6;
  int lane = tid & 63;
  int quad = lane >> 4;
  int l16 = lane & 15;
  int pixhalf = wave & 1;               // which 16-px half of the tile
  int othalf = wave >> 1;               // which half of the 14 o-tiles
  int prow = pixhalf * 16 + l16;

  bf16x8 bfrag[4];
#pragma unroll
  for (int kk = 0; kk < 4; ++kk)
    bfrag[kk] = *(const bf16x8*)(&Bl[prow * 136 + kk * 32 + quad * 8]);

  int p = p0 + prow;
  for (int oi = 0; oi < 7; ++oi) {
    int ot = othalf * 7 + oi;
    const unsigned short* Ap = A + (ot * 16 + l16) * C_ + quad * 8;
    bf16x8 afrag[4];
#pragma unroll
    for (int kk = 0; kk < 4; ++kk)
      afrag[kk] = *(const bf16x8*)(Ap + kk * 32);

    f32x4 acc = {0.f, 0.f, 0.f, 0.f};
#pragma unroll
    for (int kk = 0; kk < 4; ++kk)
      acc = __builtin_amdgcn_mfma_f32_16x16x32_bf16(afrag[kk], bfrag[kk], acc, 0, 0, 0);

    int o0 = ot * 16 + quad * 4;               // even
    float4 bv = *(const float4*)(&s_bias[o0]);
    unsigned int pk0 = (unsigned int)f2bf(acc[0] + bv.x) |
                       ((unsigned int)f2bf(acc[1] + bv.y) << 16);
    unsigned int pk1 = (unsigned int)f2bf(acc[2] + bv.z) |
                       ((unsigned int)f2bf(acc[3] + bv.w) << 16);
    unsigned int* Cp = om2 + ((size_t)n * OMROWS2_ + (o0 >> 1)) * HW_ + p;
    Cp[0] = pk0;
    Cp[HW_] = pk1;
  }
}

// ---------------------------------------------------------------------------
// K5: deformable bilinear sampling from bf16 group-planar xgb.
// ---------------------------------------------------------------------------
__global__ __launch_bounds__(256) void k_sample(const unsigned short* __restrict__ xgb,
                                                const unsigned int* __restrict__ om2,
                                                float* __restrict__ out) {
  __shared__ int4 s_wa[9 * 64];   // {pk0, pk1, off_y0, off_y1}

  int tid = threadIdx.x;
  int ord = blockIdx.x;
  int n = ord & 7;
  int t2 = ord >> 3;
  int g = t2 & 7;
  int pb = t2 >> 3;
  int p0 = pb * 64;

  const unsigned int* omb = om2 + ((size_t)n * OMROWS2_ + g * 14) * HW_ + p0;
  for (int j = tid; j < 576; j += 256) {
    int pt = j >> 6;
    int px = j & 63;
    int p = p0 + px;
    int h = p / W_;
    int w = p - h * W_;
    unsigned int od = omb[pt * HW_ + px];
    float offx = lo_bf(od);
    float offy = hi_bf(od);
    unsigned int md = omb[(9 + (pt >> 1)) * HW_ + px];
    float m = (pt & 1) ? hi_bf(md) : lo_bf(md);
    float locy = (float)(h + pt / 3 - 1) + offy;
    float locx = (float)(w + pt % 3 - 1) + offx;
    float y0f = floorf(locy);
    float x0f = floorf(locx);
    float ly = locy - y0f;
    float lx = locx - x0f;
    int y0 = (int)y0f;
    int x0 = (int)x0f;
    int y1 = y0 + 1;
    int x1 = x0 + 1;
    bool vy0 = (y0 >= 0) & (y0 < H_);
    bool vy1 = (y1 >= 0) & (y1 < H_);
    bool vx0 = (x0 >= 0) & (x0 < W_);
    bool vx1 = (x1 >= 0) & (x1 < W_);
    float t0 = (1.0f - ly) * m;
    float t1 = ly * m;
    float u0 = 1.0f - lx;
    float w00 = (vy0 & vx0) ? t0 * u0 : 0.0f;
    float w01 = (vy0 & vx1) ? t0 * lx : 0.0f;
    float w10 = (vy1 & vx0) ? t1 * u0 : 0.0f;
    float w11 = (vy1 & vx1) ? t1 * lx : 0.0f;
    int yc0 = min(max(y0, 0), H_ - 1);
    int yc1 = min(max(y1, 0), H_ - 1);
    int xs  = min(max(x0, 0), W_ - 2);
    int idx0 = min(max(x0, 0), W_ - 1) - xs;       // 0 or 1
    int idx1 = min(max(x1, 0), W_ - 1) - xs;       // 0 or 1
    float wr0y0 = (idx0 == 0 ? w00 : 0.0f) + (idx1 == 0 ? w01 : 0.0f);
    float wr1y0 = (idx0 == 1 ? w00 : 0.0f) + (idx1 == 1 ? w01 : 0.0f);
    float wr0y1 = (idx0 == 0 ? w10 : 0.0f) + (idx1 == 0 ? w11 : 0.0f);
    float wr1y1 = (idx0 == 1 ? w10 : 0.0f) + (idx1 == 1 ? w11 : 0.0f);
    int4 wa;
    wa.x = (int)((unsigned int)f2bf(wr0y0) | ((unsigned int)f2bf(wr0y1) << 16));
    wa.y = (int)((unsigned int)f2bf(wr1y0) | ((unsigned int)f2bf(wr1y1) << 16));
    wa.z = (yc0 * W_ + xs) * GC_;
    wa.w = (yc1 * W_ + xs) * GC_;
    s_wa[j] = wa;
  }
  __syncthreads();

  int px_l = tid >> 2;             // 0..63
  int sub = tid & 3;               // x-row = sub>>1, channel-chunk = sub&1
  int rowhalf = sub >> 1;
  int chunk = sub & 1;
  int p = p0 + px_l;
  const unsigned short* xbb = xgb + ((size_t)(n * G_ + g) * HW_) * GC_;

  float acc[8] = {0, 0, 0, 0, 0, 0, 0, 0};
#pragma unroll
  for (int pt = 0; pt < 9; ++pt) {
    int4 wa = s_wa[pt * 64 + px_l];
    unsigned int aw = (unsigned int)(rowhalf ? wa.y : wa.x);  // (w_y0, w_y1) bf16x2
    uint4 r0 = *(const uint4*)(xbb + wa.z + sub * 8);         // y0 row-pair
    uint4 r1 = *(const uint4*)(xbb + wa.w + sub * 8);         // y1 row-pair
    unsigned int d0[4] = {r0.x, r0.y, r0.z, r0.w};
    unsigned int d1[4] = {r1.x, r1.y, r1.z, r1.w};
#if HAVE_DOT2_
    bf16x2 a2 = u2bf2(aw);
#pragma unroll
    for (int t = 0; t < 4; ++t) {
      unsigned int blo = __builtin_amdgcn_perm(d1[t], d0[t], 0x05040100u); // (v0.lo, v1.lo)
      unsigned int bhi = __builtin_amdgcn_perm(d1[t], d0[t], 0x07060302u); // (v0.hi, v1.hi)
      acc[2 * t]     = __builtin_amdgcn_fdot2_f32_bf16(a2, u2bf2(blo), acc[2 * t], false);
      acc[2 * t + 1] = __builtin_amdgcn_fdot2_f32_bf16(a2, u2bf2(bhi), acc[2 * t + 1], false);
    }
#else
    float w0 = lo_bf(aw);
    float w1 = hi_bf(aw);
#pragma unroll
    for (int t = 0; t < 4; ++t) {
      acc[2 * t]     = fmaf(w0, lo_bf(d0[t]), acc[2 * t]);
      acc[2 * t + 1] = fmaf(w0, hi_bf(d0[t]), acc[2 * t + 1]);
      acc[2 * t]     = fmaf(w1, lo_bf(d1[t]), acc[2 * t]);
      acc[2 * t + 1] = fmaf(w1, hi_bf(d1[t]), acc[2 * t + 1]);
    }
#endif
  }

  // fold the two x-rows (lanes sub and sub^2 hold the same 8 channels)
#pragma unroll
  for (int i = 0; i < 8; ++i) acc[i] += __shfl_xor(acc[i], 2);

  int ch = chunk * 8 + rowhalf * 4;
  float* op = out + ((size_t)(n * C_ + g * GC_ + ch)) * HW_ + p;
#pragma unroll
  for (int r = 0; r < 4; ++r) op[r * HW_] = acc[rowhalf * 4 + r];
}

// ---------------------------------------------------------------------------
extern "C" void kernel_launch(void* const* d_in, const int* in_sizes, int n_in,
                              void* d_out, int out_size, void* d_ws, size_t ws_size,
                              hipStream_t stream) {
  const float* x    = (const float*)d_in[0];
  const float* dw_w = (const float*)d_in[1];
  const float* dw_b = (const float*)d_in[2];
  const float* gn_w = (const float*)d_in[3];
  const float* gn_b = (const float*)d_in[4];
  const float* om_w = (const float*)d_in[5];
  const float* om_b = (const float*)d_in[6];
  float* out = (float*)d_out;

  // workspace layout (~71 MB)
  unsigned short* xgb = (unsigned short*)d_ws;                       // 9437184 us
  unsigned short* x1b = xgb + (size_t)N_ * CHW_;                     // 9437184 us
  unsigned int* om2 = (unsigned int*)(x1b + (size_t)N_ * CHW_);      // 8*112*9216 u32
  float* stats = (float*)(om2 + (size_t)N_ * OMROWS2_ * HW_);        // 16 f
  float2* partials = (float2*)(stats + 16);                          // 1536 float2
  unsigned short* Abf = (unsigned short*)(partials + N_ * BLKS_PER_N_);
  float* biasp = (float*)(Abf + OMP_ * C_);                          // 224 f

  k_front<<<dim3(24, G_, N_), dim3(32, 8), 0, stream>>>(
      x, dw_w, dw_b, xgb, x1b, partials);
  k_stats_prep<<<N_ + 112, 256, 0, stream>>>(partials, stats, om_w, om_b, Abf, biasp);
  k_gemm_mfma<<<dim3(HW_ / 32, N_), 256, 0, stream>>>(
      x1b, Abf, biasp, stats, gn_w, gn_b, om2);
  k_sample<<<9216, 256, 0, stream>>>(xgb, om2, out);
}